// Round 2
// baseline (828.293 us; speedup 1.0000x reference)
//
#include <hip/hip_runtime.h>
#include <hip/hip_bf16.h>

#define BQ 16      // batches
#define NG 64      // groups (query tokens)
#define SQ 4096    // sequence tokens
#define CD 768     // channels
#define ROWS (BQ*NG)

// ---------------------------------------------------------------------------
// Generic 64x64-tile GEMM over K=768: out[r,c] = sum_k A[r,k]*B(k,c) (+bias)
// TRANSB: B is [N][K] (use B[c][k]);  else B is [K][N].
// BIAS_MODE: 0 none, 1 plain (+bias[c]), 2 cnt-scaled (Ksum epilogue).
// fp32 FMA with per-chunk fp32 partials accumulated into fp64 masters
// (keeps score-path error ~2e-6 so the later argmax matches the reference).
// ---------------------------------------------------------------------------
template<bool TRANSB, int BIAS_MODE>
__global__ __launch_bounds__(256)
void gemm_k768(const float* __restrict__ A, const float* __restrict__ B,
               const float* __restrict__ bias, const int* __restrict__ cnt,
               float* __restrict__ outp)
{
    __shared__ float At[64][65];   // [r-local][k-local], stride 65 -> 2-way max
    __shared__ float Bt[64][65];   // NT: [c][k]; NN: [k][c]
    const int tid  = threadIdx.x;
    const int r0   = blockIdx.y * 64;
    const int c0   = blockIdx.x * 64;
    const int rg   = tid & 15;     // 16 row-groups * 4 rows
    const int cg   = tid >> 4;     // 16 col-groups * 4 cols
    const int lrow = tid >> 4;     // staging row within pass
    const int c4   = tid & 15;     // staging float4 column

    float  accC[4][4];
    double acc64[4][4];
#pragma unroll
    for (int i = 0; i < 4; ++i)
#pragma unroll
        for (int j = 0; j < 4; ++j) { accC[i][j] = 0.f; acc64[i][j] = 0.0; }

    for (int kc = 0; kc < CD; kc += 64) {
#pragma unroll
        for (int p = 0; p < 4; ++p) {
            const int row = p * 16 + lrow;
            const float4 v = *(const float4*)(A + (size_t)(r0 + row) * CD + kc + 4 * c4);
            At[row][4*c4+0] = v.x; At[row][4*c4+1] = v.y;
            At[row][4*c4+2] = v.z; At[row][4*c4+3] = v.w;
        }
#pragma unroll
        for (int p = 0; p < 4; ++p) {
            const int row = p * 16 + lrow;
            const float4 v = TRANSB
                ? *(const float4*)(B + (size_t)(c0 + row) * CD + kc + 4 * c4)
                : *(const float4*)(B + (size_t)(kc + row) * CD + c0 + 4 * c4);
            Bt[row][4*c4+0] = v.x; Bt[row][4*c4+1] = v.y;
            Bt[row][4*c4+2] = v.z; Bt[row][4*c4+3] = v.w;
        }
        __syncthreads();
#pragma unroll 4
        for (int dd = 0; dd < 64; ++dd) {
            float a[4], b[4];
#pragma unroll
            for (int i = 0; i < 4; ++i) a[i] = At[4*rg + i][dd];
#pragma unroll
            for (int j = 0; j < 4; ++j)
                b[j] = TRANSB ? Bt[4*cg + j][dd] : Bt[dd][4*cg + j];
#pragma unroll
            for (int i = 0; i < 4; ++i)
#pragma unroll
                for (int j = 0; j < 4; ++j) accC[i][j] += a[i] * b[j];
        }
        __syncthreads();
#pragma unroll
        for (int i = 0; i < 4; ++i)
#pragma unroll
            for (int j = 0; j < 4; ++j) { acc64[i][j] += (double)accC[i][j]; accC[i][j] = 0.f; }
    }

#pragma unroll
    for (int i = 0; i < 4; ++i) {
        const int r = r0 + 4 * rg + i;
        float invf = 1.f, bsc = 0.f;
        if (BIAS_MODE == 2) {
            const int cv = cnt[r];
            invf = 1.f / ((float)cv + 1.f);   // ASSIGN_EPS = 1
            bsc  = (float)cv * invf;
        }
#pragma unroll
        for (int j = 0; j < 4; ++j) {
            const int c = c0 + 4 * cg + j;
            float v = (float)acc64[i][j];
            if (BIAS_MODE == 1)      v += bias[c];
            else if (BIAS_MODE == 2) v = v * invf + bsc * bias[c];
            outp[(size_t)r * CD + c] = v;
        }
    }
}

// ---------------------------------------------------------------------------
// delta[r] = q[r,:] . bk  (fp64) — per-n additive score term from the k-bias
// ---------------------------------------------------------------------------
__global__ __launch_bounds__(256)
void row_dot_bk(const float* __restrict__ q, const float* __restrict__ bk,
                double* __restrict__ delta)
{
    const int r    = blockIdx.x * 4 + (threadIdx.x >> 6);
    const int lane = threadIdx.x & 63;
    double acc = 0.0;
    for (int c = lane; c < CD; c += 64)
        acc += (double)q[(size_t)r * CD + c] * (double)bk[c];
    for (int off = 32; off; off >>= 1) acc += __shfl_down(acc, off, 64);
    if (lane == 0) delta[r] = acc;
}

// ---------------------------------------------------------------------------
// score_argmax: per (b, 128-s tile): S[n][s] = g[b,n,:].key[b,s,:] (+delta[n]),
// argmax over n (fp64 compare, strict > ascending n = numpy tie-break),
// writes idx[b,s], atomically bumps cnt[b,n].
// ---------------------------------------------------------------------------
struct ScoreTiles { float gt[64][68]; float kt[64][132]; };   // [k][n], [k][s]
struct ScoreRed   { double bval[128][17]; int bidx[128][17]; };
union  ScoreShared { ScoreTiles t; ScoreRed r; };

__global__ __launch_bounds__(256)
void score_argmax(const float* __restrict__ g, const float* __restrict__ key,
                  const double* __restrict__ delta, int* __restrict__ idxo,
                  int* __restrict__ cnt)
{
    __shared__ alignas(16) ScoreShared sh;
    __shared__ double dl[64];
    const int tid  = threadIdx.x;
    const int b    = blockIdx.y;
    const int s0   = blockIdx.x * 128;
    const int sg   = tid & 15;    // s = 8*sg + j
    const int ng   = tid >> 4;    // n = 4*ng + i
    const int lrow = tid >> 4;
    const int c4   = tid & 15;

    if (tid < 64) dl[tid] = delta[b * 64 + tid];

    float  accC[4][8];
    double acc64[4][8];
#pragma unroll
    for (int i = 0; i < 4; ++i)
#pragma unroll
        for (int j = 0; j < 8; ++j) { accC[i][j] = 0.f; acc64[i][j] = 0.0; }

    for (int kc = 0; kc < CD; kc += 64) {
        // stage g transposed: gt[k-local][n]
#pragma unroll
        for (int p = 0; p < 4; ++p) {
            const int nrow = p * 16 + lrow;
            const float4 v = *(const float4*)(g + (size_t)(b * 64 + nrow) * CD + kc + 4 * c4);
            sh.t.gt[4*c4+0][nrow] = v.x; sh.t.gt[4*c4+1][nrow] = v.y;
            sh.t.gt[4*c4+2][nrow] = v.z; sh.t.gt[4*c4+3][nrow] = v.w;
        }
        // stage key transposed: kt[k-local][s]
#pragma unroll
        for (int p = 0; p < 8; ++p) {
            const int srow = p * 16 + lrow;
            const float4 v = *(const float4*)(key + (size_t)(b * SQ + s0 + srow) * CD + kc + 4 * c4);
            sh.t.kt[4*c4+0][srow] = v.x; sh.t.kt[4*c4+1][srow] = v.y;
            sh.t.kt[4*c4+2][srow] = v.z; sh.t.kt[4*c4+3][srow] = v.w;
        }
        __syncthreads();
#pragma unroll 4
        for (int dd = 0; dd < 64; ++dd) {
            const float4 ga = *(const float4*)&sh.t.gt[dd][4 * ng];
            const float4 k0 = *(const float4*)&sh.t.kt[dd][8 * sg];
            const float4 k1 = *(const float4*)&sh.t.kt[dd][8 * sg + 4];
            const float gs[4] = { ga.x, ga.y, ga.z, ga.w };
            const float ks[8] = { k0.x, k0.y, k0.z, k0.w, k1.x, k1.y, k1.z, k1.w };
#pragma unroll
            for (int i = 0; i < 4; ++i)
#pragma unroll
                for (int j = 0; j < 8; ++j) accC[i][j] += gs[i] * ks[j];
        }
        __syncthreads();
#pragma unroll
        for (int i = 0; i < 4; ++i)
#pragma unroll
            for (int j = 0; j < 8; ++j) { acc64[i][j] += (double)accC[i][j]; accC[i][j] = 0.f; }
    }

    // per-thread best over its 4 n, ascending (first-index wins on ties)
    double bv[8]; int bn[8];
#pragma unroll
    for (int j = 0; j < 8; ++j) {
        bv[j] = acc64[0][j] + dl[4 * ng + 0]; bn[j] = 4 * ng + 0;
#pragma unroll
        for (int i = 1; i < 4; ++i) {
            const double v = acc64[i][j] + dl[4 * ng + i];
            if (v > bv[j]) { bv[j] = v; bn[j] = 4 * ng + i; }
        }
    }
    __syncthreads();   // tiles dead; safe to reuse union
#pragma unroll
    for (int j = 0; j < 8; ++j) {
        sh.r.bval[8 * sg + j][ng] = bv[j];
        sh.r.bidx[8 * sg + j][ng] = bn[j];
    }
    __syncthreads();
    if (tid < 128) {
        const int s = tid;
        double best = sh.r.bval[s][0]; int bi = sh.r.bidx[s][0];
        for (int k = 1; k < 16; ++k) {          // ascending n-groups: tie-break ok
            const double v = sh.r.bval[s][k];
            if (v > best) { best = v; bi = sh.r.bidx[s][k]; }
        }
        idxo[b * SQ + s0 + s] = bi;
        atomicAdd(&cnt[b * 64 + bi], 1);
    }
}

// ---------------------------------------------------------------------------
// scatter_ksum: Ksum[b,n,c-chunk] += sum over assigned s of key[b,s,c-chunk]
// grid (CD/32, B, 4 s-quarters); LDS-privatized per block, global atomic merge.
// ---------------------------------------------------------------------------
__global__ __launch_bounds__(256)
void scatter_ksum(const float* __restrict__ key, const int* __restrict__ idx,
                  float* __restrict__ Ksum)
{
    __shared__ float part[64][32];   // 8 KB, banks = c -> conflict-free
    const int b  = blockIdx.y;
    const int c0 = blockIdx.x * 32;
    const int z  = blockIdx.z;
    const int lc = threadIdx.x & 31;
    const int sl = threadIdx.x >> 5;   // 8 s-slices
    for (int t = threadIdx.x; t < 64 * 32; t += 256) ((float*)part)[t] = 0.f;
    __syncthreads();
    const int sEnd = (z + 1) * 1024;
    for (int s = z * 1024 + sl; s < sEnd; s += 8) {
        const int n = idx[b * SQ + s];
        const float v = key[(size_t)(b * SQ + s) * CD + c0 + lc];
        atomicAdd(&part[n][lc], v);
    }
    __syncthreads();
    for (int t = threadIdx.x; t < 64 * 32; t += 256) {
        const int n = t >> 5, c = t & 31;
        atomicAdd(&Ksum[(size_t)(b * 64 + n) * CD + c0 + c], part[n][c]);
    }
}

// ---------------------------------------------------------------------------
extern "C" void kernel_launch(void* const* d_in, const int* in_sizes, int n_in,
                              void* d_out, int out_size, void* d_ws, size_t ws_size,
                              hipStream_t stream)
{
    const float* query = (const float*)d_in[0];
    const float* key   = (const float*)d_in[1];
    const float* Wq    = (const float*)d_in[2];
    const float* bq    = (const float*)d_in[3];
    const float* Wk    = (const float*)d_in[4];
    const float* bk    = (const float*)d_in[5];
    const float* Wv    = (const float*)d_in[6];
    const float* bv    = (const float*)d_in[7];
    const float* Wo    = (const float*)d_in[8];
    const float* bo    = (const float*)d_in[9];

    char* ws = (char*)d_ws;
    // layout: [cnt 4KB][Ksum 3MB][delta 8KB][q 3MB][g 3MB][T1 3MB][idx 256KB]
    int*    cnt   = (int*)   (ws + 0);
    float*  Ksum  = (float*) (ws + 4096);
    double* delta = (double*)(ws + 3149824);
    float*  q     = (float*) (ws + 3158016);
    float*  g     = (float*) (ws + 6303744);
    float*  T1    = (float*) (ws + 9449472);
    int*    idx   = (int*)   (ws + 12595200);

    // zero cnt + Ksum (contiguous)
    hipMemsetAsync(d_ws, 0, 3149824, stream);

    const dim3 gg(CD / 64, ROWS / 64);   // (12,16)

    // q = query @ Wq^T + bq
    gemm_k768<true, 1><<<gg, 256, 0, stream>>>(query, Wq, bq, nullptr, q);
    // delta[r] = q[r] . bk
    row_dot_bk<<<ROWS / 4, 256, 0, stream>>>(q, bk, delta);
    // g = q @ Wk   (so score[n,s] = g[n].key[s] + delta[n]; SCALE argmax-invariant)
    gemm_k768<false, 0><<<gg, 256, 0, stream>>>(q, Wk, nullptr, nullptr, g);
    // argmax assignment + counts
    score_argmax<<<dim3(SQ / 128, BQ), 256, 0, stream>>>(g, key, delta, idx, cnt);
    // Ksum[b,n,:] = sum of assigned key rows
    scatter_ksum<<<dim3(CD / 32, BQ, 4), 256, 0, stream>>>(key, idx, Ksum);
    // T1 = (Ksum @ Wv^T)/(cnt+1) + cnt/(cnt+1)*bv
    gemm_k768<true, 2><<<gg, 256, 0, stream>>>(Ksum, Wv, bv, cnt, T1);
    // out = T1 @ Wo^T + bo   (fp32 — reference output dtype is float32)
    gemm_k768<true, 1><<<gg, 256, 0, stream>>>(T1, Wo, bo, nullptr, (float*)d_out);
}

// Round 3
// 613.146 us; speedup vs baseline: 1.3509x; 1.3509x over previous
//
#include <hip/hip_runtime.h>
#include <hip/hip_bf16.h>

#define BQ 16      // batches
#define NG 64      // groups (query tokens)
#define SQ 4096    // sequence tokens
#define CD 768     // channels
#define ROWS (BQ*NG)

// ---------------------------------------------------------------------------
// Generic 64x64-tile GEMM over K=768: out[r,c] = sum_k A[r,k]*B(k,c) (+bias)
// TRANSB: B is [N][K] (use B[c][k]);  else B is [K][N].
// BIAS_MODE: 0 none, 1 plain (+bias[c]), 2 cnt-scaled (Ksum epilogue).
// ---------------------------------------------------------------------------
template<bool TRANSB, int BIAS_MODE>
__global__ __launch_bounds__(256)
void gemm_k768(const float* __restrict__ A, const float* __restrict__ B,
               const float* __restrict__ bias, const int* __restrict__ cnt,
               float* __restrict__ outp)
{
    __shared__ float At[64][65];
    __shared__ float Bt[64][65];
    const int tid  = threadIdx.x;
    const int r0   = blockIdx.y * 64;
    const int c0   = blockIdx.x * 64;
    const int rg   = tid & 15;
    const int cg   = tid >> 4;
    const int lrow = tid >> 4;
    const int c4   = tid & 15;

    float  accC[4][4];
    double acc64[4][4];
#pragma unroll
    for (int i = 0; i < 4; ++i)
#pragma unroll
        for (int j = 0; j < 4; ++j) { accC[i][j] = 0.f; acc64[i][j] = 0.0; }

    for (int kc = 0; kc < CD; kc += 64) {
#pragma unroll
        for (int p = 0; p < 4; ++p) {
            const int row = p * 16 + lrow;
            const float4 v = *(const float4*)(A + (size_t)(r0 + row) * CD + kc + 4 * c4);
            At[row][4*c4+0] = v.x; At[row][4*c4+1] = v.y;
            At[row][4*c4+2] = v.z; At[row][4*c4+3] = v.w;
        }
#pragma unroll
        for (int p = 0; p < 4; ++p) {
            const int row = p * 16 + lrow;
            const float4 v = TRANSB
                ? *(const float4*)(B + (size_t)(c0 + row) * CD + kc + 4 * c4)
                : *(const float4*)(B + (size_t)(kc + row) * CD + c0 + 4 * c4);
            Bt[row][4*c4+0] = v.x; Bt[row][4*c4+1] = v.y;
            Bt[row][4*c4+2] = v.z; Bt[row][4*c4+3] = v.w;
        }
        __syncthreads();
#pragma unroll 4
        for (int dd = 0; dd < 64; ++dd) {
            float a[4], b[4];
#pragma unroll
            for (int i = 0; i < 4; ++i) a[i] = At[4*rg + i][dd];
#pragma unroll
            for (int j = 0; j < 4; ++j)
                b[j] = TRANSB ? Bt[4*cg + j][dd] : Bt[dd][4*cg + j];
#pragma unroll
            for (int i = 0; i < 4; ++i)
#pragma unroll
                for (int j = 0; j < 4; ++j) accC[i][j] += a[i] * b[j];
        }
        __syncthreads();
#pragma unroll
        for (int i = 0; i < 4; ++i)
#pragma unroll
            for (int j = 0; j < 4; ++j) { acc64[i][j] += (double)accC[i][j]; accC[i][j] = 0.f; }
    }

#pragma unroll
    for (int i = 0; i < 4; ++i) {
        const int r = r0 + 4 * rg + i;
        float invf = 1.f, bsc = 0.f;
        if (BIAS_MODE == 2) {
            const int cv = cnt[r];
            invf = 1.f / ((float)cv + 1.f);   // ASSIGN_EPS = 1
            bsc  = (float)cv * invf;
        }
#pragma unroll
        for (int j = 0; j < 4; ++j) {
            const int c = c0 + 4 * cg + j;
            float v = (float)acc64[i][j];
            if (BIAS_MODE == 1)      v += bias[c];
            else if (BIAS_MODE == 2) v = v * invf + bsc * bias[c];
            outp[(size_t)r * CD + c] = v;
        }
    }
}

// ---------------------------------------------------------------------------
// delta[r] = q[r,:] . bk  (fp64)
// ---------------------------------------------------------------------------
__global__ __launch_bounds__(256)
void row_dot_bk(const float* __restrict__ q, const float* __restrict__ bk,
                double* __restrict__ delta)
{
    const int r    = blockIdx.x * 4 + (threadIdx.x >> 6);
    const int lane = threadIdx.x & 63;
    double acc = 0.0;
    for (int c = lane; c < CD; c += 64)
        acc += (double)q[(size_t)r * CD + c] * (double)bk[c];
    for (int off = 32; off; off >>= 1) acc += __shfl_down(acc, off, 64);
    if (lane == 0) delta[r] = acc;
}

// ---------------------------------------------------------------------------
// score_argmax: per (b, 128-s tile): S[n][s] = g[b,n,:].key[b,s,:] (+delta[n]),
// fp64 argmax over n (strict > ascending n = numpy tie-break), writes idx[b,s].
// ---------------------------------------------------------------------------
struct ScoreTiles { float gt[64][68]; float kt[64][132]; };
struct ScoreRed   { double bval[128][17]; int bidx[128][17]; };
union  ScoreShared { ScoreTiles t; ScoreRed r; };

__global__ __launch_bounds__(256)
void score_argmax(const float* __restrict__ g, const float* __restrict__ key,
                  const double* __restrict__ delta, int* __restrict__ idxo)
{
    __shared__ alignas(16) ScoreShared sh;
    __shared__ double dl[64];
    const int tid  = threadIdx.x;
    const int b    = blockIdx.y;
    const int s0   = blockIdx.x * 128;
    const int sg   = tid & 15;
    const int ng   = tid >> 4;
    const int lrow = tid >> 4;
    const int c4   = tid & 15;

    if (tid < 64) dl[tid] = delta[b * 64 + tid];

    float  accC[4][8];
    double acc64[4][8];
#pragma unroll
    for (int i = 0; i < 4; ++i)
#pragma unroll
        for (int j = 0; j < 8; ++j) { accC[i][j] = 0.f; acc64[i][j] = 0.0; }

    for (int kc = 0; kc < CD; kc += 64) {
#pragma unroll
        for (int p = 0; p < 4; ++p) {
            const int nrow = p * 16 + lrow;
            const float4 v = *(const float4*)(g + (size_t)(b * 64 + nrow) * CD + kc + 4 * c4);
            sh.t.gt[4*c4+0][nrow] = v.x; sh.t.gt[4*c4+1][nrow] = v.y;
            sh.t.gt[4*c4+2][nrow] = v.z; sh.t.gt[4*c4+3][nrow] = v.w;
        }
#pragma unroll
        for (int p = 0; p < 8; ++p) {
            const int srow = p * 16 + lrow;
            const float4 v = *(const float4*)(key + (size_t)(b * SQ + s0 + srow) * CD + kc + 4 * c4);
            sh.t.kt[4*c4+0][srow] = v.x; sh.t.kt[4*c4+1][srow] = v.y;
            sh.t.kt[4*c4+2][srow] = v.z; sh.t.kt[4*c4+3][srow] = v.w;
        }
        __syncthreads();
#pragma unroll 4
        for (int dd = 0; dd < 64; ++dd) {
            const float4 ga = *(const float4*)&sh.t.gt[dd][4 * ng];
            const float4 k0 = *(const float4*)&sh.t.kt[dd][8 * sg];
            const float4 k1 = *(const float4*)&sh.t.kt[dd][8 * sg + 4];
            const float gs[4] = { ga.x, ga.y, ga.z, ga.w };
            const float ks[8] = { k0.x, k0.y, k0.z, k0.w, k1.x, k1.y, k1.z, k1.w };
#pragma unroll
            for (int i = 0; i < 4; ++i)
#pragma unroll
                for (int j = 0; j < 8; ++j) accC[i][j] += gs[i] * ks[j];
        }
        __syncthreads();
#pragma unroll
        for (int i = 0; i < 4; ++i)
#pragma unroll
            for (int j = 0; j < 8; ++j) { acc64[i][j] += (double)accC[i][j]; accC[i][j] = 0.f; }
    }

    double bv[8]; int bn[8];
#pragma unroll
    for (int j = 0; j < 8; ++j) {
        bv[j] = acc64[0][j] + dl[4 * ng + 0]; bn[j] = 4 * ng + 0;
#pragma unroll
        for (int i = 1; i < 4; ++i) {
            const double v = acc64[i][j] + dl[4 * ng + i];
            if (v > bv[j]) { bv[j] = v; bn[j] = 4 * ng + i; }
        }
    }
    __syncthreads();
#pragma unroll
    for (int j = 0; j < 8; ++j) {
        sh.r.bval[8 * sg + j][ng] = bv[j];
        sh.r.bidx[8 * sg + j][ng] = bn[j];
    }
    __syncthreads();
    if (tid < 128) {
        const int s = tid;
        double best = sh.r.bval[s][0]; int bi = sh.r.bidx[s][0];
        for (int k = 1; k < 16; ++k) {
            const double v = sh.r.bval[s][k];
            if (v > best) { best = v; bi = sh.r.bidx[s][k]; }
        }
        idxo[b * SQ + s0 + s] = bi;
    }
}

// ---------------------------------------------------------------------------
// gather_ksum: one block per (b,n). Scan idx[b,:], build match list in LDS,
// then gather+sum assigned key rows with coalesced loads (thread t owns
// columns t, t+256, t+512; fp64 accumulators -> order-independent result).
// Writes Ksum[b,n,:] and cnt[b,n] (= list length). No global atomics.
// ---------------------------------------------------------------------------
__global__ __launch_bounds__(256)
void gather_ksum(const float* __restrict__ key, const int* __restrict__ idx,
                 float* __restrict__ Ksum, int* __restrict__ cnt)
{
    __shared__ int slist[SQ];
    __shared__ int scount;
    const int n   = blockIdx.x;
    const int b   = blockIdx.y;
    const int tid = threadIdx.x;
    if (tid == 0) scount = 0;
    __syncthreads();

    const int* ib = idx + b * SQ;
#pragma unroll
    for (int p = 0; p < SQ / 256; ++p) {
        const int s = p * 256 + tid;
        if (ib[s] == n) {
            const int pos = atomicAdd(&scount, 1);
            slist[pos] = s;
        }
    }
    __syncthreads();
    const int m = scount;

    double a0 = 0.0, a1 = 0.0, a2 = 0.0;
    const float* kb = key + (size_t)b * SQ * CD;
    const int c1 = tid + 256, c2 = tid + 512;

    int r = 0;
    for (; r + 4 <= m; r += 4) {
        const int s0 = slist[r], s1 = slist[r + 1], s2 = slist[r + 2], s3 = slist[r + 3];
        const float* p0 = kb + (size_t)s0 * CD;
        const float* p1 = kb + (size_t)s1 * CD;
        const float* p2 = kb + (size_t)s2 * CD;
        const float* p3 = kb + (size_t)s3 * CD;
        const float v00 = p0[tid], v01 = p0[c1], v02 = p0[c2];
        const float v10 = p1[tid], v11 = p1[c1], v12 = p1[c2];
        const float v20 = p2[tid], v21 = p2[c1], v22 = p2[c2];
        const float v30 = p3[tid], v31 = p3[c1], v32 = p3[c2];
        a0 += (double)v00 + (double)v10 + (double)v20 + (double)v30;
        a1 += (double)v01 + (double)v11 + (double)v21 + (double)v31;
        a2 += (double)v02 + (double)v12 + (double)v22 + (double)v32;
    }
    for (; r < m; ++r) {
        const float* p0 = kb + (size_t)slist[r] * CD;
        a0 += (double)p0[tid]; a1 += (double)p0[c1]; a2 += (double)p0[c2];
    }

    float* out = Ksum + (size_t)(b * 64 + n) * CD;
    out[tid] = (float)a0; out[c1] = (float)a1; out[c2] = (float)a2;
    if (tid == 0) cnt[b * 64 + n] = m;
}

// ---------------------------------------------------------------------------
extern "C" void kernel_launch(void* const* d_in, const int* in_sizes, int n_in,
                              void* d_out, int out_size, void* d_ws, size_t ws_size,
                              hipStream_t stream)
{
    const float* query = (const float*)d_in[0];
    const float* key   = (const float*)d_in[1];
    const float* Wq    = (const float*)d_in[2];
    const float* bq    = (const float*)d_in[3];
    const float* Wk    = (const float*)d_in[4];
    const float* bk    = (const float*)d_in[5];
    const float* Wv    = (const float*)d_in[6];
    const float* bv    = (const float*)d_in[7];
    const float* Wo    = (const float*)d_in[8];
    const float* bo    = (const float*)d_in[9];

    char* ws = (char*)d_ws;
    // layout: [cnt 4KB][Ksum 3MB][delta 8KB][q 3MB][g 3MB][T1 3MB][idx 256KB]
    int*    cnt   = (int*)   (ws + 0);
    float*  Ksum  = (float*) (ws + 4096);
    double* delta = (double*)(ws + 3149824);
    float*  q     = (float*) (ws + 3158016);
    float*  g     = (float*) (ws + 6303744);
    float*  T1    = (float*) (ws + 9449472);
    int*    idx   = (int*)   (ws + 12595200);

    const dim3 gg(CD / 64, ROWS / 64);   // (12,16)

    // q = query @ Wq^T + bq
    gemm_k768<true, 1><<<gg, 256, 0, stream>>>(query, Wq, bq, nullptr, q);
    // delta[r] = q[r] . bk
    row_dot_bk<<<ROWS / 4, 256, 0, stream>>>(q, bk, delta);
    // g = q @ Wk   (score[n,s] = g[n].key[s] + delta[n]; SCALE argmax-invariant)
    gemm_k768<false, 0><<<gg, 256, 0, stream>>>(q, Wk, nullptr, nullptr, g);
    // argmax assignment
    score_argmax<<<dim3(SQ / 128, BQ), 256, 0, stream>>>(g, key, delta, idx);
    // Ksum[b,n,:] = sum of assigned key rows; cnt[b,n] = #assigned
    gather_ksum<<<dim3(NG, BQ), 256, 0, stream>>>(key, idx, Ksum, cnt);
    // T1 = (Ksum @ Wv^T)/(cnt+1) + cnt/(cnt+1)*bv
    gemm_k768<true, 2><<<gg, 256, 0, stream>>>(Ksum, Wv, bv, cnt, T1);
    // out = T1 @ Wo^T + bo
    gemm_k768<true, 1><<<gg, 256, 0, stream>>>(T1, Wo, bo, nullptr, (float*)d_out);
}